// Round 5
// baseline (7295.379 us; speedup 1.0000x reference)
//
#include <hip/hip_runtime.h>

#define T_STEPS 2048
#define NBATCH  1024
#define HID     32

// sigmoid(v) = 1/(1 + 2^(-1.442695*v))   (v_exp_f32 is 2^x native)
__device__ __forceinline__ float sigm(float v) {
    float e = exp2f(-1.442695040888963f * v);
    return __builtin_amdgcn_rcpf(1.0f + e);
}
// tanh(v) = 1 - 2/(1 + 2^(2.885390*v));  saturates correctly at +/-inf
__device__ __forceinline__ float tanh_fast(float v) {
    float e = exp2f(2.885390081777927f * v);
    return fmaf(-2.0f, __builtin_amdgcn_rcpf(1.0f + e), 1.0f);
}
// wave-uniform read of lane l's value
__device__ __forceinline__ float rl(float v, int l) {
    return __uint_as_float((unsigned)__builtin_amdgcn_readlane(__float_as_uint(v), l));
}

// 4 FMAs of a float4 weight against uniform h array (constant indices)
#define FMAQ(acc, W_, hs, q)                                                 \
    acc = fmaf((W_).x, hs[4*(q)+0], acc);                                    \
    acc = fmaf((W_).y, hs[4*(q)+1], acc);                                    \
    acc = fmaf((W_).z, hs[4*(q)+2], acc);                                    \
    acc = fmaf((W_).w, hs[4*(q)+3], acc);

// One block per batch element. 256 threads: thread = (half, g) where
// g = gate row (0..127), half = k-half (0..1). Each thread holds 16-wide
// slices of its 5 weight rows (80 VGPRs). Gate half-partials exchanged via
// LDS (3 barriers/step); h vectors broadcast via v_readlane (16/layer).
// FC reduce for step t-1 is software-pipelined across step t's phase gaps.
__global__ __launch_bounds__(256, 2)
void lstm3_fc_kernel(const float* __restrict__ x,
                     const float* __restrict__ Wih0, const float* __restrict__ Whh0,
                     const float* __restrict__ bih0, const float* __restrict__ bhh0,
                     const float* __restrict__ Wih1, const float* __restrict__ Whh1,
                     const float* __restrict__ bih1, const float* __restrict__ bhh1,
                     const float* __restrict__ Wih2, const float* __restrict__ Whh2,
                     const float* __restrict__ bih2, const float* __restrict__ bhh2,
                     const float* __restrict__ Wfc,  const float* __restrict__ bfc,
                     float* __restrict__ out)
{
    const int t0   = threadIdx.x;       // 0..255
    const int g    = t0 & 127;          // gate row
    const int half = t0 >> 7;           // k-half
    const int j    = t0 & 31;           // unit id (replicated 8x)
    const int ko   = half * 16;         // k offset
    const int b    = blockIdx.x;

    const float4* pw0 = (const float4*)(Whh0 + g * HID + ko);
    const float4* pw1 = (const float4*)(Wih1 + g * HID + ko);
    const float4* pw2 = (const float4*)(Whh1 + g * HID + ko);
    const float4* pw3 = (const float4*)(Wih2 + g * HID + ko);
    const float4* pw4 = (const float4*)(Whh2 + g * HID + ko);
    float4 w0a = pw0[0], w0b = pw0[1], w0c = pw0[2], w0d = pw0[3];
    float4 w1a = pw1[0], w1b = pw1[1], w1c = pw1[2], w1d = pw1[3];
    float4 w2a = pw2[0], w2b = pw2[1], w2c = pw2[2], w2d = pw2[3];
    float4 w3a = pw3[0], w3b = pw3[1], w3c = pw3[2], w3d = pw3[3];
    float4 w4a = pw4[0], w4b = pw4[1], w4c = pw4[2], w4d = pw4[3];

    const float wih0g = Wih0[g];                      // Wih0 is (128,1)
    const float bias0 = (half == 0) ? (bih0[g] + bhh0[g]) : 0.0f;
    const float bias1 = (half == 0) ? (bih1[g] + bhh1[g]) : 0.0f;
    const float bias2 = (half == 0) ? (bih2[g] + bhh2[g]) : 0.0f;
    const float wfcg  = Wfc[j];
    const float bfc0  = bfc[0];

    __shared__ float GT0[256], GT1[256], GT2[256];

    float h0s[16], h1s[16], h2s[16];                  // wave-uniform h slices
#pragma unroll
    for (int k = 0; k < 16; ++k) { h0s[k] = 0.f; h1s[k] = 0.f; h2s[k] = 0.f; }
    float c0 = 0.f, c1 = 0.f, c2 = 0.f;               // cell state of unit j
    float vprev = 0.f, r2 = 0.f, r4 = 0.f;            // FC reduce pipeline

    float xt = x[b];
    for (int t = 0; t < T_STEPS; ++t) {
        const int tn = (t + 1 < T_STEPS) ? (t + 1) : t;
        const float xnext = x[tn * NBATCH + b];

        // ---- layer 0 half-dot: Whh0[g][ko:ko+16) @ h0(old) ----
        float a0 = (half == 0) ? fmaf(wih0g, xt, bias0) : 0.0f;
        float a1 = 0.f, a2 = 0.f, a3 = 0.f;
        FMAQ(a0, w0a, h0s, 0) FMAQ(a1, w0b, h0s, 1)
        FMAQ(a2, w0c, h0s, 2) FMAQ(a3, w0d, h0s, 3)
        GT0[t0] = (a0 + a1) + (a2 + a3);
        // FC pipe stage A (for step t-1); latency hides under barrier+L0upd
        float rA = vprev + __shfl_xor(vprev, 1);
        r2 = rA + __shfl_xor(rA, 2);
        __syncthreads();
        // ---- layer 0 cell update (replicated 8x) ----
        {
            float gi = GT0[j]      + GT0[j + 128];
            float gf = GT0[j + 32] + GT0[j + 160];
            float gg = GT0[j + 64] + GT0[j + 192];
            float go = GT0[j + 96] + GT0[j + 224];
            float ii = sigm(gi), ff = sigm(gf), gz = tanh_fast(gg), oo = sigm(go);
            c0 = fmaf(ff, c0, ii * gz);
            float h0v = oo * tanh_fast(c0);           // lane holds h0[j]
#pragma unroll
            for (int k = 0; k < 16; ++k) h0s[k] = rl(h0v, ko + k);
        }

        // ---- layer 1 half-dot: Wih1 @ h0(new) + Whh1 @ h1(old) ----
        a0 = bias1; a1 = 0.f; a2 = 0.f; a3 = 0.f;
        FMAQ(a0, w1a, h0s, 0) FMAQ(a1, w1b, h0s, 1)
        FMAQ(a2, w1c, h0s, 2) FMAQ(a3, w1d, h0s, 3)
        FMAQ(a0, w2a, h1s, 0) FMAQ(a1, w2b, h1s, 1)
        FMAQ(a2, w2c, h1s, 2) FMAQ(a3, w2d, h1s, 3)
        GT1[t0] = (a0 + a1) + (a2 + a3);
        // FC pipe stage B
        float rB = r2 + __shfl_xor(r2, 4);
        r4 = rB + __shfl_xor(rB, 8);
        __syncthreads();
        // ---- layer 1 cell update ----
        {
            float gi = GT1[j]      + GT1[j + 128];
            float gf = GT1[j + 32] + GT1[j + 160];
            float gg = GT1[j + 64] + GT1[j + 192];
            float go = GT1[j + 96] + GT1[j + 224];
            float ii = sigm(gi), ff = sigm(gf), gz = tanh_fast(gg), oo = sigm(go);
            c1 = fmaf(ff, c1, ii * gz);
            float h1v = oo * tanh_fast(c1);
#pragma unroll
            for (int k = 0; k < 16; ++k) h1s[k] = rl(h1v, ko + k);
        }

        // ---- layer 2 half-dot: Wih2 @ h1(new) + Whh2 @ h2(old) ----
        a0 = bias2; a1 = 0.f; a2 = 0.f; a3 = 0.f;
        FMAQ(a0, w3a, h1s, 0) FMAQ(a1, w3b, h1s, 1)
        FMAQ(a2, w3c, h1s, 2) FMAQ(a3, w3d, h1s, 3)
        FMAQ(a0, w4a, h2s, 0) FMAQ(a1, w4b, h2s, 1)
        FMAQ(a2, w4c, h2s, 2) FMAQ(a3, w4d, h2s, 3)
        GT2[t0] = (a0 + a1) + (a2 + a3);
        // FC pipe stage C + store of out[t-1]
        float rC = r4 + __shfl_xor(r4, 16);
        float rD = rC + __shfl_xor(rC, 32);           // 64-lane sum = 2*dot
        if (t > 0 && t0 == 0) out[(t - 1) * NBATCH + b] = fmaf(0.5f, rD, bfc0);
        __syncthreads();
        // ---- layer 2 cell update ----
        {
            float gi = GT2[j]      + GT2[j + 128];
            float gf = GT2[j + 32] + GT2[j + 160];
            float gg = GT2[j + 64] + GT2[j + 192];
            float go = GT2[j + 96] + GT2[j + 224];
            float ii = sigm(gi), ff = sigm(gf), gz = tanh_fast(gg), oo = sigm(go);
            c2 = fmaf(ff, c2, ii * gz);
            float h2v = oo * tanh_fast(c2);
#pragma unroll
            for (int k = 0; k < 16; ++k) h2s[k] = rl(h2v, ko + k);
            vprev = wfcg * h2v;                       // FC partial for step t
        }

        xt = xnext;
    }

    // epilogue: finish FC reduce for t = T-1
    float rA = vprev + __shfl_xor(vprev, 1);
    rA += __shfl_xor(rA, 2);
    rA += __shfl_xor(rA, 4);
    rA += __shfl_xor(rA, 8);
    rA += __shfl_xor(rA, 16);
    rA += __shfl_xor(rA, 32);
    if (t0 == 0) out[(T_STEPS - 1) * NBATCH + b] = fmaf(0.5f, rA, bfc0);
}

extern "C" void kernel_launch(void* const* d_in, const int* in_sizes, int n_in,
                              void* d_out, int out_size, void* d_ws, size_t ws_size,
                              hipStream_t stream)
{
    const float* x    = (const float*)d_in[0];
    const float* Wih0 = (const float*)d_in[1];
    const float* Whh0 = (const float*)d_in[2];
    const float* bih0 = (const float*)d_in[3];
    const float* bhh0 = (const float*)d_in[4];
    const float* Wih1 = (const float*)d_in[5];
    const float* Whh1 = (const float*)d_in[6];
    const float* bih1 = (const float*)d_in[7];
    const float* bhh1 = (const float*)d_in[8];
    const float* Wih2 = (const float*)d_in[9];
    const float* Whh2 = (const float*)d_in[10];
    const float* bih2 = (const float*)d_in[11];
    const float* bhh2 = (const float*)d_in[12];
    const float* Wfc  = (const float*)d_in[13];
    const float* bfc  = (const float*)d_in[14];
    float* out        = (float*)d_out;

    lstm3_fc_kernel<<<dim3(NBATCH), dim3(256), 0, stream>>>(
        x, Wih0, Whh0, bih0, bhh0,
        Wih1, Whh1, bih1, bhh1,
        Wih2, Whh2, bih2, bhh2,
        Wfc, bfc, out);
}

// Round 6
// 7153.802 us; speedup vs baseline: 1.0198x; 1.0198x over previous
//
#include <hip/hip_runtime.h>

#define T_STEPS 2048
#define NBATCH  1024

typedef _Float16 f16x8 __attribute__((ext_vector_type(8)));
typedef float    f32x4 __attribute__((ext_vector_type(4)));

__device__ __forceinline__ float sigm(float v) {
    float e = exp2f(-1.442695040888963f * v);
    return __builtin_amdgcn_rcpf(1.0f + e);
}
__device__ __forceinline__ float tanh_fast(float v) {
    float e = exp2f(2.885390081777927f * v);
    return fmaf(-2.0f, __builtin_amdgcn_rcpf(1.0f + e), 1.0f);
}

// load 8 consecutive fp32 -> 8 fp16 (RNE) fragment
__device__ __forceinline__ f16x8 loadrow8(const float* p) {
    float4 lo = *reinterpret_cast<const float4*>(p);
    float4 hi = *reinterpret_cast<const float4*>(p + 4);
    f16x8 r;
    r[0] = (_Float16)lo.x; r[1] = (_Float16)lo.y;
    r[2] = (_Float16)lo.z; r[3] = (_Float16)lo.w;
    r[4] = (_Float16)hi.x; r[5] = (_Float16)hi.y;
    r[6] = (_Float16)hi.z; r[7] = (_Float16)hi.w;
    return r;
}

// One block = one wave = 16 batch columns for all T steps.
// Gate-row permutation: perm row r <-> (m = r>>4, gp = (r&15)>>2, q = r&3),
// original row = q*32 + 8*gp + m  (unit u = 8*gp + m, gate q).
// MFMA C-layout (col=lane&15=batch, row=(lane>>4)*4+reg): lane l, tile m holds
// i,f,g,o of unit 8*(l>>4)+m for batch l&15 in its 4 acc regs -> in-lane cell
// update. The 8 per-tile h results ARE the lane's next B-frag elements
// (B: k = 8*(l>>4)+e, n = l&15) -> zero cross-lane in the recurrence.
__global__ __launch_bounds__(64, 1)
void lstm3_mfma_kernel(const float* __restrict__ x,
                       const float* __restrict__ Wih0, const float* __restrict__ Whh0,
                       const float* __restrict__ bih0, const float* __restrict__ bhh0,
                       const float* __restrict__ Wih1, const float* __restrict__ Whh1,
                       const float* __restrict__ bih1, const float* __restrict__ bhh1,
                       const float* __restrict__ Wih2, const float* __restrict__ Whh2,
                       const float* __restrict__ bih2, const float* __restrict__ bhh2,
                       const float* __restrict__ Wfc,  const float* __restrict__ bfc,
                       float* __restrict__ out)
{
    const int l  = threadIdx.x;       // 0..63
    const int g  = l >> 4;            // lane group (k-chunk / C row-group)
    const int b  = l & 15;            // batch column within tile
    const int qa = l & 3;             // gate index for A-row loads
    const int gp = (l & 15) >> 2;     // unit group for A-row loads
    const int b0 = blockIdx.x * 16;   // batch-tile base

    // ---- A fragments (weights, fp16), resident for all 2048 steps ----
    f16x8 F0[8], F1i[8], F1h[8], F2i[8], F2h[8];
#pragma unroll
    for (int m = 0; m < 8; ++m) {
        const int rowA = qa * 32 + 8 * gp + m;   // original gate-row
        const int k0   = 8 * g;                  // k-slice
        F0[m]  = loadrow8(Whh0 + rowA * 32 + k0);
        F1i[m] = loadrow8(Wih1 + rowA * 32 + k0);
        F1h[m] = loadrow8(Whh1 + rowA * 32 + k0);
        F2i[m] = loadrow8(Wih2 + rowA * 32 + k0);
        F2h[m] = loadrow8(Whh2 + rowA * 32 + k0);
    }

    // ---- biases & Wih0 column in C-layout, staggered in LDS (conflict-free
    // broadcast reads: addr = (9g+m)*16, distinct banks per lane group) ----
    __shared__ float sb0[144], sb1[144], sb2[144], sw0[144];
    for (int e = l; e < 128; e += 64) {
        const int u = e >> 2, r = e & 3;
        const int idx = (u + (u >> 3)) * 4 + r;
        sb0[idx] = bih0[r * 32 + u] + bhh0[r * 32 + u];
        sb1[idx] = bih1[r * 32 + u] + bhh1[r * 32 + u];
        sb2[idx] = bih2[r * 32 + u] + bhh2[r * 32 + u];
        sw0[idx] = Wih0[r * 32 + u];
    }
    __syncthreads();

    float wfc[8];
#pragma unroll
    for (int m = 0; m < 8; ++m) wfc[m] = Wfc[8 * g + m];
    const float bfc0 = bfc[0];

    f16x8 hb0 = {0, 0, 0, 0, 0, 0, 0, 0};   // h as B-fragments (fp16)
    f16x8 hb1 = {0, 0, 0, 0, 0, 0, 0, 0};
    f16x8 hb2 = {0, 0, 0, 0, 0, 0, 0, 0};
    float c0[8], c1[8], c2[8];
#pragma unroll
    for (int m = 0; m < 8; ++m) { c0[m] = 0.f; c1[m] = 0.f; c2[m] = 0.f; }

    float xv = x[b0 + b];
    for (int t = 0; t < T_STEPS; ++t) {
        const int tn = (t + 1 < T_STEPS) ? t + 1 : t;
        const float xn = x[tn * NBATCH + b0 + b];   // prefetch next step's x

        f32x4 acc[8];
        float hn[8];

        // ================= layer 0: gates = Whh0 @ h0 (+ Wih0*x + b) =======
#pragma unroll
        for (int m = 0; m < 8; ++m) {
            f32x4 z = {0.f, 0.f, 0.f, 0.f};
            acc[m] = __builtin_amdgcn_mfma_f32_16x16x32_f16(F0[m], hb0, z, 0, 0, 0);
        }
#pragma unroll
        for (int m = 0; m < 8; ++m) {
            const float4 bb = *reinterpret_cast<const float4*>(&sb0[(9 * g + m) * 4]);
            const float4 w0 = *reinterpret_cast<const float4*>(&sw0[(9 * g + m) * 4]);
            const float gi = fmaf(w0.x, xv, acc[m][0] + bb.x);
            const float gf = fmaf(w0.y, xv, acc[m][1] + bb.y);
            const float gg = fmaf(w0.z, xv, acc[m][2] + bb.z);
            const float go = fmaf(w0.w, xv, acc[m][3] + bb.w);
            const float ii = sigm(gi), ff = sigm(gf);
            const float gz = tanh_fast(gg), oo = sigm(go);
            c0[m] = fmaf(ff, c0[m], ii * gz);
            hn[m] = oo * tanh_fast(c0[m]);
        }
#pragma unroll
        for (int m = 0; m < 8; ++m) hb0[m] = (_Float16)hn[m];

        // ================= layer 1: gates = Wih1 @ h0new + Whh1 @ h1old ====
#pragma unroll
        for (int m = 0; m < 8; ++m) {
            f32x4 z = {0.f, 0.f, 0.f, 0.f};
            z      = __builtin_amdgcn_mfma_f32_16x16x32_f16(F1i[m], hb0, z, 0, 0, 0);
            acc[m] = __builtin_amdgcn_mfma_f32_16x16x32_f16(F1h[m], hb1, z, 0, 0, 0);
        }
#pragma unroll
        for (int m = 0; m < 8; ++m) {
            const float4 bb = *reinterpret_cast<const float4*>(&sb1[(9 * g + m) * 4]);
            const float gi = acc[m][0] + bb.x;
            const float gf = acc[m][1] + bb.y;
            const float gg = acc[m][2] + bb.z;
            const float go = acc[m][3] + bb.w;
            const float ii = sigm(gi), ff = sigm(gf);
            const float gz = tanh_fast(gg), oo = sigm(go);
            c1[m] = fmaf(ff, c1[m], ii * gz);
            hn[m] = oo * tanh_fast(c1[m]);
        }
#pragma unroll
        for (int m = 0; m < 8; ++m) hb1[m] = (_Float16)hn[m];

        // ================= layer 2: gates = Wih2 @ h1new + Whh2 @ h2old ====
#pragma unroll
        for (int m = 0; m < 8; ++m) {
            f32x4 z = {0.f, 0.f, 0.f, 0.f};
            z      = __builtin_amdgcn_mfma_f32_16x16x32_f16(F2i[m], hb1, z, 0, 0, 0);
            acc[m] = __builtin_amdgcn_mfma_f32_16x16x32_f16(F2h[m], hb2, z, 0, 0, 0);
        }
#pragma unroll
        for (int m = 0; m < 8; ++m) {
            const float4 bb = *reinterpret_cast<const float4*>(&sb2[(9 * g + m) * 4]);
            const float gi = acc[m][0] + bb.x;
            const float gf = acc[m][1] + bb.y;
            const float gg = acc[m][2] + bb.z;
            const float go = acc[m][3] + bb.w;
            const float ii = sigm(gi), ff = sigm(gf);
            const float gz = tanh_fast(gg), oo = sigm(go);
            c2[m] = fmaf(ff, c2[m], ii * gz);
            hn[m] = oo * tanh_fast(c2[m]);
        }
#pragma unroll
        for (int m = 0; m < 8; ++m) hb2[m] = (_Float16)hn[m];

        // ================= fused FC: out[t][b] = Wfc @ h2 + bfc ============
        float v = 0.f;
#pragma unroll
        for (int m = 0; m < 8; ++m) v = fmaf(wfc[m], hn[m], v);
        v += __shfl_xor(v, 16);      // sum the 4 lane-groups (units 0..31)
        v += __shfl_xor(v, 32);
        if (l < 16) out[t * NBATCH + b0 + l] = v + bfc0;

        xv = xn;
    }
}

extern "C" void kernel_launch(void* const* d_in, const int* in_sizes, int n_in,
                              void* d_out, int out_size, void* d_ws, size_t ws_size,
                              hipStream_t stream)
{
    const float* x    = (const float*)d_in[0];
    const float* Wih0 = (const float*)d_in[1];
    const float* Whh0 = (const float*)d_in[2];
    const float* bih0 = (const float*)d_in[3];
    const float* bhh0 = (const float*)d_in[4];
    const float* Wih1 = (const float*)d_in[5];
    const float* Whh1 = (const float*)d_in[6];
    const float* bih1 = (const float*)d_in[7];
    const float* bhh1 = (const float*)d_in[8];
    const float* Wih2 = (const float*)d_in[9];
    const float* Whh2 = (const float*)d_in[10];
    const float* bih2 = (const float*)d_in[11];
    const float* bhh2 = (const float*)d_in[12];
    const float* Wfc  = (const float*)d_in[13];
    const float* bfc  = (const float*)d_in[14];
    float* out        = (float*)d_out;

    lstm3_mfma_kernel<<<dim3(NBATCH / 16), dim3(64), 0, stream>>>(
        x, Wih0, Whh0, bih0, bhh0,
        Wih1, Whh1, bih1, bhh1,
        Wih2, Whh2, bih2, bhh2,
        Wfc, bfc, out);
}